// Round 1
// baseline (17.508 us; speedup 1.0000x reference)
//
#include <hip/hip_runtime.h>
#include <hip/hip_bf16.h>

// Masked one-hot: out[b,n,c] = (labels[b,n] == c) ? 1.0f : 0.0f, rows with
// label < 0 stay all zeros. Pure write-bound: 79.6 MB out, 128 KB labels in.
// Each thread writes one float4 (4 consecutive output elems, 16B-aligned).

#define BB 256
#define NN 128
#define CC 607

__global__ __launch_bounds__(256) void onehot_kernel(const int* __restrict__ labels,
                                                     float* __restrict__ out,
                                                     int n_vec4) {
    int t = blockIdx.x * blockDim.x + threadIdx.x;
    if (t >= n_vec4) return;
    int base = t * 4;  // flat element index of first of 4

    float4 v;
    float* vp = &v.x;
#pragma unroll
    for (int j = 0; j < 4; ++j) {
        int idx = base + j;
        int row = (int)((unsigned)idx / (unsigned)CC);   // magic-mul division
        int c   = idx - row * CC;
        int lab = labels[row];                           // L1/L2 broadcast
        vp[j] = (c == lab) ? 1.0f : 0.0f;                // lab<0 never matches
    }
    *reinterpret_cast<float4*>(out + base) = v;
}

extern "C" void kernel_launch(void* const* d_in, const int* in_sizes, int n_in,
                              void* d_out, int out_size, void* d_ws, size_t ws_size,
                              hipStream_t stream) {
    // d_in[0] = obj_sem_cls_pred (float32, unused — only dtype/shape matter)
    // d_in[1] = obj_labels (int32 on device; JAX x64 disabled downcasts int64)
    // d_in[2] = cur_step, d_in[3] = total_steps (unused by reference output)
    const int* labels = (const int*)d_in[1];
    float* out = (float*)d_out;

    const int total = BB * NN * CC;          // 19,890,176 (divisible by 4)
    const int n_vec4 = total / 4;            // 4,972,544
    const int block = 256;
    const int grid = (n_vec4 + block - 1) / block;   // 19424 blocks

    onehot_kernel<<<grid, block, 0, stream>>>(labels, out, n_vec4);
}